// Round 3
// baseline (943.674 us; speedup 1.0000x reference)
//
#include <hip/hip_runtime.h>

typedef unsigned short u16;
typedef __attribute__((ext_vector_type(8))) short s8v;   // 8 bf16 (4 VGPRs) MFMA A/B frag
typedef __attribute__((ext_vector_type(4))) float f4v;   // MFMA C/D frag

#define MFMA16(a, b, c) __builtin_amdgcn_mfma_f32_16x16x32_bf16((a), (b), (c), 0, 0, 0)

__device__ inline float bf2f(u16 h) { return __uint_as_float(((unsigned)h) << 16); }
__device__ inline u16 f2bf(float f) {
    unsigned u = __float_as_uint(f);
    u += 0x7FFFu + ((u >> 16) & 1u);   // round-to-nearest-even
    return (u16)(u >> 16);
}

// ---------------------------------------------------------------------------
// Kernel 0: dtype probe. Even-indexed u16s of fp32 data are mantissa halves
// (log-uniform exponent -> "insane" magnitudes); of bf16 N(0,1) data they are
// sane values. flag=1 -> inputs are fp32.
// ---------------------------------------------------------------------------
__global__ void probe_kernel(const u16* __restrict__ x16, int* __restrict__ flag) {
    int lane = threadIdx.x;
    int cnt = 0;
    for (int i = lane; i < 2048; i += 64) {
        float v = bf2f(x16[2 * i]);
        float a = fabsf(v);
        bool sane = (a == 0.0f) || (a > 1e-5f && a < 1e5f);  // NaN -> false
        if (!sane) cnt++;
    }
#pragma unroll
    for (int off = 32; off; off >>= 1) cnt += __shfl_xor(cnt, off);
    if (lane == 0) flag[0] = (cnt > 512) ? 1 : 0;
}

// ---------------------------------------------------------------------------
// Kernel 0b: weight convert (fp32->bf16) or copy (bf16->bf16). 8 elems/thread.
// ---------------------------------------------------------------------------
__global__ __launch_bounds__(256) void convert_kernel(const void* __restrict__ src,
                                                      u16* __restrict__ dst,
                                                      const int* __restrict__ flagp) {
    int f = *flagp;
    int base = (blockIdx.x * 256 + threadIdx.x) * 8;
    if (f) {
        const float* s = (const float*)src;
        float4 a = *(const float4*)(s + base);
        float4 b = *(const float4*)(s + base + 4);
        u16 o[8] = {f2bf(a.x), f2bf(a.y), f2bf(a.z), f2bf(a.w),
                    f2bf(b.x), f2bf(b.y), f2bf(b.z), f2bf(b.w)};
        *(uint4*)(dst + base) = *(const uint4*)o;
    } else {
        *(uint4*)(dst + base) = *(const uint4*)((const u16*)src + base);
    }
}

// ---------------------------------------------------------------------------
// Kernel 1: LayerNorm (adaptive fp32/bf16 in, bf16 out), one block per row
// ---------------------------------------------------------------------------
__global__ __launch_bounds__(256) void ln_kernel(const void* __restrict__ xv,
                                                 const void* __restrict__ gv,
                                                 const void* __restrict__ bv,
                                                 u16* __restrict__ xn,
                                                 const int* __restrict__ flagp) {
    int f = *flagp;
    int row = blockIdx.x;
    int tid = threadIdx.x;
    int lane = tid & 63, wave = tid >> 6;

    float v[4];
    if (f) {
        const float* xr = (const float*)xv + (size_t)row * 1024;
        float4 a = ((const float4*)xr)[tid];
        v[0] = a.x; v[1] = a.y; v[2] = a.z; v[3] = a.w;
    } else {
        const u16* xr = (const u16*)xv + (size_t)row * 1024;
        uint2 raw = ((const uint2*)xr)[tid];
        v[0] = bf2f((u16)(raw.x & 0xffff));
        v[1] = bf2f((u16)(raw.x >> 16));
        v[2] = bf2f((u16)(raw.y & 0xffff));
        v[3] = bf2f((u16)(raw.y >> 16));
    }

    float s = v[0] + v[1] + v[2] + v[3];
    float ss = v[0]*v[0] + v[1]*v[1] + v[2]*v[2] + v[3]*v[3];
#pragma unroll
    for (int off = 32; off; off >>= 1) {
        s  += __shfl_xor(s, off);
        ss += __shfl_xor(ss, off);
    }
    __shared__ float red[8];
    if (lane == 0) { red[wave] = s; red[4 + wave] = ss; }
    __syncthreads();
    s  = red[0] + red[1] + red[2] + red[3];
    ss = red[4] + red[5] + red[6] + red[7];

    float mu  = s * (1.0f / 1024.0f);
    float var = ss * (1.0f / 1024.0f) - mu * mu;
    float rs  = rsqrtf(var + 1e-5f);

    u16 o[4];
#pragma unroll
    for (int i = 0; i < 4; i++) {
        int c = tid * 4 + i;
        float g = f ? ((const float*)gv)[c] : bf2f(((const u16*)gv)[c]);
        float b = f ? ((const float*)bv)[c] : bf2f(((const u16*)bv)[c]);
        float y = (v[i] - mu) * rs * g + b;
        o[i] = f2bf(y);
    }
    uint2 packed;
    packed.x = (unsigned)o[0] | ((unsigned)o[1] << 16);
    packed.y = (unsigned)o[2] | ((unsigned)o[3] << 16);
    ((uint2*)(xn + (size_t)row * 1024))[tid] = packed;
}

// ---------------------------------------------------------------------------
// Kernel 2/4: GEMM  C[M,N] = A[M,K] @ W[K,N]   (bf16 in, fp32 acc)
// BM=BN=128, BK=32, 256 threads = 4 waves, each wave a 64x64 quadrant.
// MODE 0: scatter epilogue -> q,k as [b,h,n,d], v as [b,h,d,n] (bf16, to ws)
// MODE 1: FP32 out: out[gm*N+gn] = acc + b_out[gn]  (d_out is float*!)
// ---------------------------------------------------------------------------
template <int MODE>
__global__ __launch_bounds__(256) void gemm_kernel(const u16* __restrict__ A,
                                                   const u16* __restrict__ W,
                                                   const void* __restrict__ bias,
                                                   const int* __restrict__ flagp,
                                                   void* __restrict__ outv,
                                                   int M, int N, int K) {
    __shared__ __align__(16) u16 As[128][40];   // [m][k], +8 pad
    __shared__ __align__(16) u16 Bs[128][40];   // [n][k], +8 pad

    int tid = threadIdx.x;
    int lane = tid & 63, wave = tid >> 6;
    int quad = lane >> 4, l16 = lane & 15;
    int wr = wave >> 1, wc = wave & 1;
    int m0 = blockIdx.y * 128, n0 = blockIdx.x * 128;

    f4v acc[4][4];
#pragma unroll
    for (int i = 0; i < 4; i++)
#pragma unroll
        for (int j = 0; j < 4; j++) acc[i][j] = (f4v){0.f, 0.f, 0.f, 0.f};

    for (int k0 = 0; k0 < K; k0 += 32) {
        __syncthreads();
        // stage A tile: 128 rows x 32 k, 8 bf16 per chunk
#pragma unroll
        for (int c = tid; c < 512; c += 256) {
            int row = c >> 2, kk = (c & 3) * 8;
            uint4 r = *(const uint4*)(A + (size_t)(m0 + row) * K + k0 + kk);
            *(uint4*)&As[row][kk] = r;
        }
        // stage W tile transposed: read [k][n-contig], scatter into Bs[n][k]
#pragma unroll
        for (int c = tid; c < 512; c += 256) {
            int kr = c >> 4, nc = (c & 15) * 8;
            uint4 r = *(const uint4*)(W + (size_t)(k0 + kr) * N + n0 + nc);
            const u16* p = (const u16*)&r;
#pragma unroll
            for (int i = 0; i < 8; i++) Bs[nc + i][kr] = p[i];
        }
        __syncthreads();

        s8v afr[4], bfr[4];
#pragma unroll
        for (int mi = 0; mi < 4; mi++)
            afr[mi] = *(const s8v*)&As[wr * 64 + mi * 16 + l16][quad * 8];
#pragma unroll
        for (int ni = 0; ni < 4; ni++)
            bfr[ni] = *(const s8v*)&Bs[wc * 64 + ni * 16 + l16][quad * 8];
#pragma unroll
        for (int mi = 0; mi < 4; mi++)
#pragma unroll
            for (int ni = 0; ni < 4; ni++)
                acc[mi][ni] = MFMA16(afr[mi], bfr[ni], acc[mi][ni]);
    }

    int f = (MODE == 1) ? *flagp : 0;

    // epilogue: C/D layout col=lane&15, row=quad*4+reg
#pragma unroll
    for (int mi = 0; mi < 4; mi++) {
#pragma unroll
        for (int ni = 0; ni < 4; ni++) {
#pragma unroll
            for (int r = 0; r < 4; r++) {
                int gm = m0 + wr * 64 + mi * 16 + quad * 4 + r;
                int gn = n0 + wc * 64 + ni * 16 + l16;
                float v = acc[mi][ni][r];
                if (MODE == 1) {
                    // d_out is FP32 (reference output dtype is float32)
                    float bb = f ? ((const float*)bias)[gn]
                                 : bf2f(((const u16*)bias)[gn]);
                    ((float*)outv)[(size_t)gm * N + gn] = v + bb;
                } else {
                    u16* out = (u16*)outv;
                    int sel = gn >> 10, rem = gn & 1023;
                    int h = rem >> 6, d = rem & 63;
                    int b = gm >> 11, q = gm & 2047;
                    size_t dst;
                    if (sel == 2)  // v transposed: [b,h,d,n]
                        dst = ((size_t)(b * 16 + h) * 64 + d) * 2048 + q;
                    else           // q,k: [b,h,n,d]
                        dst = ((size_t)(b * 16 + h) * 2048 + q) * 64 + d;
                    out[(size_t)sel * 8388608 + dst] = f2bf(v);
                }
            }
        }
    }
}

// ---------------------------------------------------------------------------
// Kernel 3: flash attention. Block = 64 q-rows of one (b,h); 4 waves x 16 rows.
// K stored [b,h,n,d]; V stored transposed [b,h,d,n]; bias adaptive fp32/bf16.
// ---------------------------------------------------------------------------
__global__ __launch_bounds__(256) void attn_kernel(const u16* __restrict__ qg,
                                                   const u16* __restrict__ kg,
                                                   const u16* __restrict__ vtg,
                                                   const void* __restrict__ bias,
                                                   const int* __restrict__ flagp,
                                                   u16* __restrict__ out) {
    int bid = blockIdx.x;                 // (qt*16 + h)*4 + b  -> b fastest for bias L2 reuse
    int b = bid & 3, h = (bid >> 2) & 15, qt = bid >> 6;
    int q0 = qt * 64;
    int bh = b * 16 + h;
    int f = *flagp;

    int tid = threadIdx.x;
    int lane = tid & 63, wave = tid >> 6;
    int quad = lane >> 4, l16 = lane & 15;

    __shared__ __align__(16) u16 Ks[64][72];       // [kcol][kd]
    __shared__ __align__(16) u16 Vt[64][72];       // [d][kv]
    __shared__ __align__(16) u16 Ps[4][16][72];    // per-wave P round-trip

    // Q fragments: constant across K loop. A-layout: m = l16, k = quad*8+j
    const u16* qrow = qg + ((size_t)bh * 2048 + q0 + wave * 16 + l16) * 64;
    s8v qf0 = *(const s8v*)(qrow + quad * 8);
    s8v qf1 = *(const s8v*)(qrow + 32 + quad * 8);

    f4v oacc[4];
#pragma unroll
    for (int i = 0; i < 4; i++) oacc[i] = (f4v){0.f, 0.f, 0.f, 0.f};
    float mrow[4] = {-1e30f, -1e30f, -1e30f, -1e30f};
    float lrow[4] = {0.f, 0.f, 0.f, 0.f};

    const u16* kbase = kg + (size_t)bh * 2048 * 64;
    const u16* vbase = vtg + (size_t)bh * 64 * 2048;
    size_t boff = ((size_t)h * 2048 + q0 + wave * 16 + quad * 4) * 2048;
    const float* bbf = (const float*)bias + boff;
    const u16*   bbh = (const u16*)bias + boff;

    for (int kt = 0; kt < 2048; kt += 64) {
        __syncthreads();
        // stage K tile [64][64] and Vt tile [64][64]
#pragma unroll
        for (int c = tid; c < 512; c += 256) {
            int row = c >> 3, c8 = (c & 7) * 8;
            *(uint4*)&Ks[row][c8] = *(const uint4*)(kbase + (size_t)(kt + row) * 64 + c8);
            *(uint4*)&Vt[row][c8] = *(const uint4*)(vbase + (size_t)row * 2048 + kt + c8);
        }
        __syncthreads();

        // S = Q (16x64) @ K^T (64x64): 4 col-tiles, 2 k-chunks each
        f4v sc[4];
#pragma unroll
        for (int ni = 0; ni < 4; ni++) {
            s8v k0f = *(const s8v*)&Ks[ni * 16 + l16][quad * 8];
            s8v k1f = *(const s8v*)&Ks[ni * 16 + l16][32 + quad * 8];
            f4v t = (f4v){0.f, 0.f, 0.f, 0.f};
            t = MFMA16(qf0, k0f, t);
            t = MFMA16(qf1, k1f, t);
            sc[ni] = t;
        }

        // bias fetch (adaptive), then scale+bias in fp32.
        // C-layout: row=quad*4+r, col=ni*16+l16
        float barr[4][4];   // [ni][r]
        if (f) {
#pragma unroll
            for (int r = 0; r < 4; r++)
#pragma unroll
                for (int ni = 0; ni < 4; ni++)
                    barr[ni][r] = bbf[(size_t)r * 2048 + kt + ni * 16 + l16];
        } else {
#pragma unroll
            for (int r = 0; r < 4; r++)
#pragma unroll
                for (int ni = 0; ni < 4; ni++)
                    barr[ni][r] = bf2f(bbh[(size_t)r * 2048 + kt + ni * 16 + l16]);
        }
        float sv[4][4];   // [ni][r]
#pragma unroll
        for (int r = 0; r < 4; r++)
#pragma unroll
            for (int ni = 0; ni < 4; ni++)
                sv[ni][r] = sc[ni][r] * 0.125f + barr[ni][r];

        // online softmax over this 64-col slab, per q-row r (4 rows per quad)
        float mx[4];
#pragma unroll
        for (int r = 0; r < 4; r++) {
            mx[r] = fmaxf(fmaxf(sv[0][r], sv[1][r]), fmaxf(sv[2][r], sv[3][r]));
#pragma unroll
            for (int off = 1; off < 16; off <<= 1)
                mx[r] = fmaxf(mx[r], __shfl_xor(mx[r], off));
        }
        float alpha[4], rsum[4];
#pragma unroll
        for (int r = 0; r < 4; r++) {
            float mnew = fmaxf(mrow[r], mx[r]);
            alpha[r] = __expf(mrow[r] - mnew);
            mrow[r] = mnew;
            rsum[r] = 0.f;
#pragma unroll
            for (int ni = 0; ni < 4; ni++) {
                float p = __expf(sv[ni][r] - mnew);
                rsum[r] += p;
                Ps[wave][quad * 4 + r][ni * 16 + l16] = f2bf(p);
            }
        }
#pragma unroll
        for (int r = 0; r < 4; r++) {
#pragma unroll
            for (int off = 1; off < 16; off <<= 1)
                rsum[r] += __shfl_xor(rsum[r], off);
            lrow[r] = lrow[r] * alpha[r] + rsum[r];
        }
#pragma unroll
        for (int od = 0; od < 4; od++) {
            f4v t = oacc[od];
            t[0] *= alpha[0]; t[1] *= alpha[1]; t[2] *= alpha[2]; t[3] *= alpha[3];
            oacc[od] = t;
        }
        __syncthreads();   // P visible (and Ks/Vt reads done before next staging)

        // O += P (16x64) @ V (64x16-per-od). A=P from LDS, B=V^T rows.
        s8v pf0 = *(const s8v*)&Ps[wave][l16][quad * 8];
        s8v pf1 = *(const s8v*)&Ps[wave][l16][32 + quad * 8];
#pragma unroll
        for (int od = 0; od < 4; od++) {
            s8v vf0 = *(const s8v*)&Vt[od * 16 + l16][quad * 8];
            s8v vf1 = *(const s8v*)&Vt[od * 16 + l16][32 + quad * 8];
            oacc[od] = MFMA16(pf0, vf0, oacc[od]);
            oacc[od] = MFMA16(pf1, vf1, oacc[od]);
        }
    }

    // epilogue: normalize and write attn_out [b, q, h*64+d] bf16
    float inv[4];
#pragma unroll
    for (int r = 0; r < 4; r++) inv[r] = 1.0f / lrow[r];
#pragma unroll
    for (int od = 0; od < 4; od++) {
#pragma unroll
        for (int r = 0; r < 4; r++) {
            size_t dst = ((size_t)b * 2048 + q0 + wave * 16 + quad * 4 + r) * 1024 +
                         h * 64 + od * 16 + l16;
            out[dst] = f2bf(oacc[od][r] * inv[r]);
        }
    }
}

// ---------------------------------------------------------------------------
extern "C" void kernel_launch(void* const* d_in, const int* in_sizes, int n_in,
                              void* d_out, int out_size, void* d_ws, size_t ws_size,
                              hipStream_t stream) {
    const void* x      = d_in[0];
    const void* bias   = d_in[1];
    const void* w_qkv  = d_in[2];
    const void* w_out  = d_in[3];
    const void* b_out  = d_in[4];
    const void* gamma  = d_in[5];
    const void* beta   = d_in[6];

    u16* base = (u16*)d_ws;
    int* flag = (int*)d_ws;            // 128 B reserved
    u16* xn   = base + 64;             // 8192*1024 bf16            (16 MB)
    u16* qkv  = xn + 8388608;          // 3 * [b,h,n,d]/[b,h,d,n]   (48 MB)
    u16* attn = qkv + 3 * 8388608;     // 8192*1024 bf16            (16 MB)
    u16* wqb  = attn + 8388608;        // 1024*3072 bf16            (6 MB)
    u16* wob  = wqb + 3145728;         // 1024*1024 bf16            (2 MB)

    probe_kernel<<<dim3(1), dim3(64), 0, stream>>>((const u16*)x, flag);

    ln_kernel<<<dim3(8192), dim3(256), 0, stream>>>(x, gamma, beta, xn, flag);

    convert_kernel<<<dim3(1536), dim3(256), 0, stream>>>(w_qkv, wqb, flag);
    convert_kernel<<<dim3(512),  dim3(256), 0, stream>>>(w_out, wob, flag);

    gemm_kernel<0><<<dim3(3072 / 128, 8192 / 128), dim3(256), 0, stream>>>(
        xn, wqb, nullptr, flag, qkv, 8192, 3072, 1024);

    attn_kernel<<<dim3(2048), dim3(256), 0, stream>>>(
        qkv, qkv + 8388608, qkv + 2 * 8388608, bias, flag, attn);

    gemm_kernel<1><<<dim3(1024 / 128, 8192 / 128), dim3(256), 0, stream>>>(
        attn, wob, b_out, flag, d_out, 8192, 1024, 1024);
}